// Round 1
// baseline (4216.469 us; speedup 1.0000x reference)
//
#include <hip/hip_runtime.h>
#include <cmath>

#define BDIM 32
#define TDIM 577
#define EDIM 1024
#define HDIM 16
#define DDIM 64
#define MDIM (BDIM * TDIM)  // 18464

// ---------------------------------------------------------------------------
// Tiled fp32 GEMM: C[M,N] = A[M,K] @ W[K,N] + bias, K=N=1024.
// 128x128 tile, BK=16, 256 threads, 8x8 microtile (split 4+4 to keep LDS
// fragment reads <=2-way bank aliased which is free on gfx950).
// mode 0: scatter output to [B,H,T,D] (row m -> (b,t), col n -> (h,d))
// mode 1: plain row-major [M,N] output
// grid.z selects among 3 weight/bias/dst sets (QKV in one launch).
// ---------------------------------------------------------------------------
__global__ __launch_bounds__(256) void gemm_proj(
    const float* __restrict__ A,
    const float* __restrict__ W0, const float* __restrict__ W1, const float* __restrict__ W2,
    const float* __restrict__ b0, const float* __restrict__ b1, const float* __restrict__ b2,
    float* __restrict__ o0, float* __restrict__ o1, float* __restrict__ o2,
    int mode)
{
    __shared__ float As[16][128];  // [k][m] transposed
    __shared__ float Bs[16][128];  // [k][n]

    const int z = blockIdx.z;
    const float* __restrict__ Wm   = (z == 0) ? W0 : ((z == 1) ? W1 : W2);
    const float* __restrict__ bias = (z == 0) ? b0 : ((z == 1) ? b1 : b2);
    float* __restrict__ dst        = (z == 0) ? o0 : ((z == 1) ? o1 : o2);

    const int tid = threadIdx.x;
    const int tx = tid & 15;
    const int ty = tid >> 4;
    const int m0 = blockIdx.y * 128;
    const int n0 = blockIdx.x * 128;

    float acc[8][8];
#pragma unroll
    for (int i = 0; i < 8; ++i)
#pragma unroll
        for (int j = 0; j < 8; ++j) acc[i][j] = 0.f;

    const int arow = tid >> 2;         // 0..63
    const int acol = (tid & 3) * 4;    // 0,4,8,12
    const int brow = tid >> 5;         // 0..7
    const int bcol = (tid & 31) * 4;   // 0..124

    for (int k0 = 0; k0 < EDIM; k0 += 16) {
        // Stage A tile (transposed into LDS)
#pragma unroll
        for (int p = 0; p < 2; ++p) {
            int row = p * 64 + arow;
            int gm = m0 + row;
            float4 av = make_float4(0.f, 0.f, 0.f, 0.f);
            if (gm < MDIM)
                av = *(const float4*)(A + (size_t)gm * EDIM + k0 + acol);
            As[acol + 0][row] = av.x;
            As[acol + 1][row] = av.y;
            As[acol + 2][row] = av.z;
            As[acol + 3][row] = av.w;
        }
        // Stage W tile
#pragma unroll
        for (int p = 0; p < 2; ++p) {
            int row = p * 8 + brow;
            float4 wv = *(const float4*)(Wm + (size_t)(k0 + row) * EDIM + n0 + bcol);
            *(float4*)&Bs[row][bcol] = wv;
        }
        __syncthreads();

#pragma unroll
        for (int kk = 0; kk < 16; ++kk) {
            float a[8], bb[8];
            *(float4*)&a[0]  = *(const float4*)&As[kk][ty * 4];
            *(float4*)&a[4]  = *(const float4*)&As[kk][64 + ty * 4];
            *(float4*)&bb[0] = *(const float4*)&Bs[kk][tx * 4];
            *(float4*)&bb[4] = *(const float4*)&Bs[kk][64 + tx * 4];
#pragma unroll
            for (int i = 0; i < 8; ++i)
#pragma unroll
                for (int j = 0; j < 8; ++j)
                    acc[i][j] += a[i] * bb[j];
        }
        __syncthreads();
    }

    float bv0[8];
#pragma unroll
    for (int j = 0; j < 4; ++j) {
        bv0[j]     = bias[n0 + tx * 4 + j];
        bv0[4 + j] = bias[n0 + 64 + tx * 4 + j];
    }

#pragma unroll
    for (int i = 0; i < 8; ++i) {
        int row = (i < 4) ? (ty * 4 + i) : (64 + ty * 4 + (i - 4));
        int gm = m0 + row;
        if (gm >= MDIM) continue;
        float4 v0, v1;
        v0.x = acc[i][0] + bv0[0]; v0.y = acc[i][1] + bv0[1];
        v0.z = acc[i][2] + bv0[2]; v0.w = acc[i][3] + bv0[3];
        v1.x = acc[i][4] + bv0[4]; v1.y = acc[i][5] + bv0[5];
        v1.z = acc[i][6] + bv0[6]; v1.w = acc[i][7] + bv0[7];
        if (mode == 1) {
            *(float4*)(dst + (size_t)gm * EDIM + n0 + tx * 4)      = v0;
            *(float4*)(dst + (size_t)gm * EDIM + n0 + 64 + tx * 4) = v1;
        } else {
            int b = gm / TDIM;
            int t = gm - b * TDIM;
            int nA = n0 + tx * 4;
            int hA = nA >> 6, dA = nA & 63;
            *(float4*)(dst + ((size_t)(b * HDIM + hA) * TDIM + t) * DDIM + dA) = v0;
            int nB = n0 + 64 + tx * 4;
            int hB = nB >> 6, dB = nB & 63;
            *(float4*)(dst + ((size_t)(b * HDIM + hB) * TDIM + t) * DDIM + dB) = v1;
        }
    }
}

// ---------------------------------------------------------------------------
// Flash attention, fp32. One block = one (b,h) and 64 q rows.
// KV chunks of 64; online softmax; P kept in registers, broadcast via shfl
// (avoids a P round-trip through LDS). LDS = 2*64*68*4 + 64*64*4 = 50.8 KB.
// ---------------------------------------------------------------------------
__global__ __launch_bounds__(256) void attn_fp32(
    const float* __restrict__ q, const float* __restrict__ k,
    const float* __restrict__ v, float* __restrict__ out)
{
    __shared__ float Qs[64][68];   // [d][q_row] (pad 68 to cut transpose-store conflicts)
    __shared__ float Ks[64][68];   // [d][k_row]
    __shared__ float Vs[64][64];   // [k_row][d]

    const int tid = threadIdx.x;
    const int tx = tid & 15, ty = tid >> 4;
    const int lane = tid & 63;
    const int h = blockIdx.y, b = blockIdx.z;
    const size_t base = ((size_t)b * HDIM + h) * TDIM * DDIM;
    const float* qb = q + base;
    const float* kb = k + base;
    const float* vb = v + base;
    const int q0 = blockIdx.x * 64;

    const int sr = tid >> 4;         // 0..15
    const int sc = (tid & 15) * 4;   // 0..60

    // Stage Q tile (transposed) once
#pragma unroll
    for (int p = 0; p < 4; ++p) {
        int r = p * 16 + sr;
        int gr = q0 + r;
        float4 qv = make_float4(0.f, 0.f, 0.f, 0.f);
        if (gr < TDIM) qv = *(const float4*)(qb + (size_t)gr * DDIM + sc);
        Qs[sc + 0][r] = qv.x; Qs[sc + 1][r] = qv.y;
        Qs[sc + 2][r] = qv.z; Qs[sc + 3][r] = qv.w;
    }

    float m_i[4], l_i[4], o[4][4];
#pragma unroll
    for (int i = 0; i < 4; ++i) {
        m_i[i] = -INFINITY;
        l_i[i] = 0.f;
#pragma unroll
        for (int j = 0; j < 4; ++j) o[i][j] = 0.f;
    }

    for (int kv0 = 0; kv0 < TDIM; kv0 += 64) {
        __syncthreads();  // previous chunk's reads done before overwrite
#pragma unroll
        for (int p = 0; p < 4; ++p) {
            int r = p * 16 + sr;
            int gr = kv0 + r;
            float4 kv4 = make_float4(0.f, 0.f, 0.f, 0.f);
            float4 vv4 = make_float4(0.f, 0.f, 0.f, 0.f);
            if (gr < TDIM) {
                kv4 = *(const float4*)(kb + (size_t)gr * DDIM + sc);
                vv4 = *(const float4*)(vb + (size_t)gr * DDIM + sc);
            }
            Ks[sc + 0][r] = kv4.x; Ks[sc + 1][r] = kv4.y;
            Ks[sc + 2][r] = kv4.z; Ks[sc + 3][r] = kv4.w;
            *(float4*)&Vs[r][sc] = vv4;
        }
        __syncthreads();

        // S = Q K^T (4x4 per thread over the 64x64 tile)
        float s[4][4];
#pragma unroll
        for (int i = 0; i < 4; ++i)
#pragma unroll
            for (int j = 0; j < 4; ++j) s[i][j] = 0.f;

#pragma unroll 16
        for (int dd = 0; dd < 64; ++dd) {
            float4 qa = *(const float4*)&Qs[dd][ty * 4];
            float4 ka = *(const float4*)&Ks[dd][tx * 4];
            float qv[4] = {qa.x, qa.y, qa.z, qa.w};
            float kv[4] = {ka.x, ka.y, ka.z, ka.w};
#pragma unroll
            for (int i = 0; i < 4; ++i)
#pragma unroll
                for (int j = 0; j < 4; ++j)
                    s[i][j] += qv[i] * kv[j];
        }

        // scale + mask OOB kv columns
#pragma unroll
        for (int j = 0; j < 4; ++j) {
            bool valid = (kv0 + tx * 4 + j) < TDIM;
#pragma unroll
            for (int i = 0; i < 4; ++i)
                s[i][j] = valid ? s[i][j] * 0.125f : -INFINITY;
        }

        // online softmax update (rows live on 16 lanes sharing ty)
#pragma unroll
        for (int i = 0; i < 4; ++i) {
            float cm = fmaxf(fmaxf(s[i][0], s[i][1]), fmaxf(s[i][2], s[i][3]));
            cm = fmaxf(cm, __shfl_xor(cm, 1, 64));
            cm = fmaxf(cm, __shfl_xor(cm, 2, 64));
            cm = fmaxf(cm, __shfl_xor(cm, 4, 64));
            cm = fmaxf(cm, __shfl_xor(cm, 8, 64));
            float m_new = fmaxf(m_i[i], cm);
            float alpha = __expf(m_i[i] - m_new);
            float rs = 0.f;
#pragma unroll
            for (int j = 0; j < 4; ++j) {
                s[i][j] = __expf(s[i][j] - m_new);   // -inf -> 0 for masked cols
                rs += s[i][j];
            }
            rs += __shfl_xor(rs, 1, 64);
            rs += __shfl_xor(rs, 2, 64);
            rs += __shfl_xor(rs, 4, 64);
            rs += __shfl_xor(rs, 8, 64);
            l_i[i] = l_i[i] * alpha + rs;
            m_i[i] = m_new;
#pragma unroll
            for (int j = 0; j < 4; ++j) o[i][j] *= alpha;
        }

        // O += P @ V ; P row q lives across the 16 lanes of its ty group:
        // broadcast via shfl (ds_bpermute), V read from LDS.
#pragma unroll
        for (int kc4 = 0; kc4 < 16; ++kc4) {
            int src = (lane & 48) + kc4;
#pragma unroll
            for (int jj = 0; jj < 4; ++jj) {
                float4 vv = *(const float4*)&Vs[kc4 * 4 + jj][tx * 4];
                float p0 = __shfl(s[0][jj], src, 64);
                float p1 = __shfl(s[1][jj], src, 64);
                float p2 = __shfl(s[2][jj], src, 64);
                float p3 = __shfl(s[3][jj], src, 64);
                o[0][0] += p0 * vv.x; o[0][1] += p0 * vv.y; o[0][2] += p0 * vv.z; o[0][3] += p0 * vv.w;
                o[1][0] += p1 * vv.x; o[1][1] += p1 * vv.y; o[1][2] += p1 * vv.z; o[1][3] += p1 * vv.w;
                o[2][0] += p2 * vv.x; o[2][1] += p2 * vv.y; o[2][2] += p2 * vv.z; o[2][3] += p2 * vv.w;
                o[3][0] += p3 * vv.x; o[3][1] += p3 * vv.y; o[3][2] += p3 * vv.z; o[3][3] += p3 * vv.w;
            }
        }
    }

    // epilogue: normalize and store to [B,T,E] layout
#pragma unroll
    for (int i = 0; i < 4; ++i) {
        int t = q0 + ty * 4 + i;
        if (t >= TDIM) continue;
        float inv = 1.f / l_i[i];
        float4 r;
        r.x = o[i][0] * inv; r.y = o[i][1] * inv;
        r.z = o[i][2] * inv; r.w = o[i][3] * inv;
        *(float4*)(out + ((size_t)b * TDIM + t) * EDIM + h * DDIM + tx * 4) = r;
    }
}

// ---------------------------------------------------------------------------
extern "C" void kernel_launch(void* const* d_in, const int* in_sizes, int n_in,
                              void* d_out, int out_size, void* d_ws, size_t ws_size,
                              hipStream_t stream)
{
    const float* x  = (const float*)d_in[0];
    const float* Wq = (const float*)d_in[1];
    const float* bq = (const float*)d_in[2];
    const float* Wk = (const float*)d_in[3];
    const float* bk = (const float*)d_in[4];
    const float* Wv = (const float*)d_in[5];
    const float* bv = (const float*)d_in[6];
    const float* Wo = (const float*)d_in[7];
    const float* bo = (const float*)d_in[8];
    float* out = (float*)d_out;

    const size_t qsz = (size_t)BDIM * HDIM * TDIM * DDIM;  // 18,907,136 floats
    float* qb = (float*)d_ws;
    float* kb = qb + qsz;
    float* vb = kb + qsz;
    float* ab = vb + qsz;   // attention output in [B,T,E]
    // total ws use: 4 * qsz * 4 B = 302.5 MB

    // QKV projections (fused scatter to [B,H,T,D])
    dim3 g1(EDIM / 128, (MDIM + 127) / 128, 3);   // (8, 145, 3)
    gemm_proj<<<g1, 256, 0, stream>>>(x, Wq, Wk, Wv, bq, bk, bv, qb, kb, vb, 0);

    // attention
    dim3 g2((TDIM + 63) / 64, HDIM, BDIM);        // (10, 16, 32)
    attn_fp32<<<g2, 256, 0, stream>>>(qb, kb, vb, ab);

    // output projection
    dim3 g3(EDIM / 128, (MDIM + 127) / 128, 1);
    gemm_proj<<<g3, 256, 0, stream>>>(ab, Wo, Wo, Wo, bo, bo, bo, out, out, out, 1);
}

// Round 3
// 1579.177 us; speedup vs baseline: 2.6700x; 2.6700x over previous
//
#include <hip/hip_runtime.h>
#include <cmath>

#define BDIM 32
#define TDIM 577
#define EDIM 1024
#define HDIM 16
#define DDIM 64
#define MDIM (BDIM * TDIM)     // 18464
#define MTILES 145
#define MPAD (MTILES * 128)    // 18560

typedef unsigned short u16;
typedef __bf16 bf16x8 __attribute__((ext_vector_type(8)));
typedef float f32x4 __attribute__((ext_vector_type(4)));
typedef u16 u16x8 __attribute__((ext_vector_type(8)));

// fp32 -> bf16 round-to-nearest-even (matches numpy/jax)
__device__ __forceinline__ u16 f2bf(float f) {
    unsigned int u = __float_as_uint(f);
    u = (u + 0x7FFFu + ((u >> 16) & 1u)) >> 16;
    return (u16)u;
}

// async global->LDS, 16B per lane. LDS dest must be wave-uniform base; HW adds lane*16.
__device__ __forceinline__ void gload_lds16(const void* g, void* l) {
    __builtin_amdgcn_global_load_lds(
        (const __attribute__((address_space(1))) unsigned int*)g,
        (__attribute__((address_space(3))) unsigned int*)l, 16, 0, 0);
}

// ---------------------------------------------------------------------------
// cast x (fp32 [M,E]) -> bf16, 8 elems/thread
// ---------------------------------------------------------------------------
__global__ __launch_bounds__(256) void cast_x(const float* __restrict__ x,
                                              u16* __restrict__ o, int nelem)
{
    int i = (blockIdx.x * 256 + threadIdx.x) * 8;
    if (i >= nelem) return;
    float4 a = *(const float4*)(x + i);
    float4 b = *(const float4*)(x + i + 4);
    u16x8 r;
    r[0] = f2bf(a.x); r[1] = f2bf(a.y); r[2] = f2bf(a.z); r[3] = f2bf(a.w);
    r[4] = f2bf(b.x); r[5] = f2bf(b.y); r[6] = f2bf(b.z); r[7] = f2bf(b.w);
    *(u16x8*)(o + i) = r;
}

// ---------------------------------------------------------------------------
// cast + transpose weights: W fp32 [K,N] -> Wt bf16 [N,K]. 32x32 LDS tiles.
// ---------------------------------------------------------------------------
__global__ __launch_bounds__(256) void cast_wt(
    const float* __restrict__ W0, const float* __restrict__ W1,
    const float* __restrict__ W2, const float* __restrict__ W3,
    u16* __restrict__ T0, u16* __restrict__ T1,
    u16* __restrict__ T2, u16* __restrict__ T3)
{
    __shared__ float tile[32][33];
    const int z = blockIdx.z;
    const float* __restrict__ W = (z == 0) ? W0 : (z == 1) ? W1 : (z == 2) ? W2 : W3;
    u16* __restrict__ T = (z == 0) ? T0 : (z == 1) ? T1 : (z == 2) ? T2 : T3;
    const int bn = blockIdx.x * 32;
    const int bk = blockIdx.y * 32;
    const int tx = threadIdx.x & 31, ty = threadIdx.x >> 5;  // ty 0..7
#pragma unroll
    for (int p = 0; p < 4; ++p) {
        int k = bk + p * 8 + ty;
        tile[p * 8 + ty][tx] = W[(size_t)k * EDIM + bn + tx];
    }
    __syncthreads();
#pragma unroll
    for (int p = 0; p < 4; ++p) {
        int n = bn + p * 8 + ty;
        T[(size_t)n * EDIM + bk + tx] = f2bf(tile[tx][p * 8 + ty]);
    }
}

// ---------------------------------------------------------------------------
// bf16 MFMA GEMM (m97 "gemm_bt" structure): C[M,N] = A[M,K] @ Wt[N,K]^T + bias
// 128x128 tile, BK=32, 256 thr = 4 waves, each wave 64x64 = 4x4 mfma 16x16x32.
// global_load_lds width=16 staging; LDS unpadded row-major [128][32] (lane
// order == LDS order, required by global_load_lds). ds_read_b128 fragments.
// mode 0: scatter to [B,H,T,D] fp32 (grid.z picks Wq/Wk/Wv set)
// mode 1: row-major [M,N] fp32
// ---------------------------------------------------------------------------
__global__ __launch_bounds__(256) void gemm_bf16(
    const u16* __restrict__ A,
    const u16* __restrict__ W0, const u16* __restrict__ W1, const u16* __restrict__ W2,
    const float* __restrict__ b0, const float* __restrict__ b1, const float* __restrict__ b2,
    float* __restrict__ o0, float* __restrict__ o1, float* __restrict__ o2,
    int mode)
{
    __shared__ u16 As[128 * 32];   // [m][k] row-major, 8 KB
    __shared__ u16 Bs[128 * 32];   // [n][k] row-major, 8 KB

    const int z = blockIdx.z;
    const u16* __restrict__ Wt     = (z == 0) ? W0 : ((z == 1) ? W1 : W2);
    const float* __restrict__ bias = (z == 0) ? b0 : ((z == 1) ? b1 : b2);
    float* __restrict__ dst        = (z == 0) ? o0 : ((z == 1) ? o1 : o2);

    const int tid = threadIdx.x;
    const int wave = tid >> 6;
    const int lane = tid & 63;
    const int mlane = lane & 15;
    const int quad = lane >> 4;
    const int wm = wave >> 1;            // 0..1
    const int wn = wave & 1;             // 0..1
    const int m0 = blockIdx.y * 128;
    const int n0 = blockIdx.x * 128;

    f32x4 acc[4][4];
#pragma unroll
    for (int i = 0; i < 4; ++i)
#pragma unroll
        for (int j = 0; j < 4; ++j) acc[i][j] = (f32x4)(0.f);

    for (int k0 = 0; k0 < EDIM; k0 += 32) {
#pragma unroll
        for (int r = 0; r < 2; ++r) {
            int c = r * 256 + tid;            // chunk id: row c>>2, col8 (c&3)*8
            int row = c >> 2, col = (c & 3) * 8;
            gload_lds16(A + (size_t)(m0 + row) * EDIM + k0 + col,
                        &As[(r * 256 + wave * 64) * 8]);
            gload_lds16(Wt + (size_t)(n0 + row) * EDIM + k0 + col,
                        &Bs[(r * 256 + wave * 64) * 8]);
        }
        __syncthreads();   // drains vmcnt (global_load_lds) per compiler semantics

        bf16x8 af[4], bf[4];
#pragma unroll
        for (int t = 0; t < 4; ++t) {
            af[t] = *(const bf16x8*)&As[(wm * 64 + t * 16 + mlane) * 32 + quad * 8];
            bf[t] = *(const bf16x8*)&Bs[(wn * 64 + t * 16 + mlane) * 32 + quad * 8];
        }
#pragma unroll
        for (int i = 0; i < 4; ++i)
#pragma unroll
            for (int j = 0; j < 4; ++j)
                acc[i][j] = __builtin_amdgcn_mfma_f32_16x16x32_bf16(af[i], bf[j], acc[i][j], 0, 0, 0);
        __syncthreads();
    }

    // epilogue: C/D layout col = lane&15, row = quad*4 + reg
#pragma unroll
    for (int j = 0; j < 4; ++j) {
        int n = n0 + wn * 64 + j * 16 + mlane;
        float bv = bias[n];
        if (mode == 1) {
#pragma unroll
            for (int i = 0; i < 4; ++i) {
                int mb = m0 + wm * 64 + i * 16 + quad * 4;
#pragma unroll
                for (int r = 0; r < 4; ++r) {
                    int gm = mb + r;
                    if (gm < MDIM) dst[(size_t)gm * EDIM + n] = acc[i][j][r] + bv;
                }
            }
        } else {
            int h = n >> 6, d = n & 63;
#pragma unroll
            for (int i = 0; i < 4; ++i) {
                int mb = m0 + wm * 64 + i * 16 + quad * 4;
#pragma unroll
                for (int r = 0; r < 4; ++r) {
                    int gm = mb + r;
                    if (gm < MDIM) {
                        int b = gm / TDIM, t = gm - b * TDIM;
                        dst[((size_t)(b * HDIM + h) * TDIM + t) * DDIM + d] = acc[i][j][r] + bv;
                    }
                }
            }
        }
    }
}

// ---------------------------------------------------------------------------
// Flash attention, fp32 math (unchanged from round 1); epilogue writes bf16.
// ---------------------------------------------------------------------------
__global__ __launch_bounds__(256) void attn_fp32(
    const float* __restrict__ q, const float* __restrict__ k,
    const float* __restrict__ v, u16* __restrict__ out)
{
    __shared__ float Qs[64][68];
    __shared__ float Ks[64][68];
    __shared__ float Vs[64][64];

    const int tid = threadIdx.x;
    const int tx = tid & 15, ty = tid >> 4;
    const int lane = tid & 63;
    const int h = blockIdx.y, b = blockIdx.z;
    const size_t base = ((size_t)b * HDIM + h) * TDIM * DDIM;
    const float* qb = q + base;
    const float* kb = k + base;
    const float* vb = v + base;
    const int q0 = blockIdx.x * 64;

    const int sr = tid >> 4;
    const int sc = (tid & 15) * 4;

#pragma unroll
    for (int p = 0; p < 4; ++p) {
        int r = p * 16 + sr;
        int gr = q0 + r;
        float4 qv = make_float4(0.f, 0.f, 0.f, 0.f);
        if (gr < TDIM) qv = *(const float4*)(qb + (size_t)gr * DDIM + sc);
        Qs[sc + 0][r] = qv.x; Qs[sc + 1][r] = qv.y;
        Qs[sc + 2][r] = qv.z; Qs[sc + 3][r] = qv.w;
    }

    float m_i[4], l_i[4], o[4][4];
#pragma unroll
    for (int i = 0; i < 4; ++i) {
        m_i[i] = -INFINITY;
        l_i[i] = 0.f;
#pragma unroll
        for (int j = 0; j < 4; ++j) o[i][j] = 0.f;
    }

    for (int kv0 = 0; kv0 < TDIM; kv0 += 64) {
        __syncthreads();
#pragma unroll
        for (int p = 0; p < 4; ++p) {
            int r = p * 16 + sr;
            int gr = kv0 + r;
            float4 kv4 = make_float4(0.f, 0.f, 0.f, 0.f);
            float4 vv4 = make_float4(0.f, 0.f, 0.f, 0.f);
            if (gr < TDIM) {
                kv4 = *(const float4*)(kb + (size_t)gr * DDIM + sc);
                vv4 = *(const float4*)(vb + (size_t)gr * DDIM + sc);
            }
            Ks[sc + 0][r] = kv4.x; Ks[sc + 1][r] = kv4.y;
            Ks[sc + 2][r] = kv4.z; Ks[sc + 3][r] = kv4.w;
            *(float4*)&Vs[r][sc] = vv4;
        }
        __syncthreads();

        float s[4][4];
#pragma unroll
        for (int i = 0; i < 4; ++i)
#pragma unroll
            for (int j = 0; j < 4; ++j) s[i][j] = 0.f;

#pragma unroll 16
        for (int dd = 0; dd < 64; ++dd) {
            float4 qa = *(const float4*)&Qs[dd][ty * 4];
            float4 ka = *(const float4*)&Ks[dd][tx * 4];
            float qv[4] = {qa.x, qa.y, qa.z, qa.w};
            float kv[4] = {ka.x, ka.y, ka.z, ka.w};
#pragma unroll
            for (int i = 0; i < 4; ++i)
#pragma unroll
                for (int j = 0; j < 4; ++j)
                    s[i][j] += qv[i] * kv[j];
        }

#pragma unroll
        for (int j = 0; j < 4; ++j) {
            bool valid = (kv0 + tx * 4 + j) < TDIM;
#pragma unroll
            for (int i = 0; i < 4; ++i)
                s[i][j] = valid ? s[i][j] * 0.125f : -INFINITY;
        }

#pragma unroll
        for (int i = 0; i < 4; ++i) {
            float cm = fmaxf(fmaxf(s[i][0], s[i][1]), fmaxf(s[i][2], s[i][3]));
            cm = fmaxf(cm, __shfl_xor(cm, 1, 64));
            cm = fmaxf(cm, __shfl_xor(cm, 2, 64));
            cm = fmaxf(cm, __shfl_xor(cm, 4, 64));
            cm = fmaxf(cm, __shfl_xor(cm, 8, 64));
            float m_new = fmaxf(m_i[i], cm);
            float alpha = __expf(m_i[i] - m_new);
            float rs = 0.f;
#pragma unroll
            for (int j = 0; j < 4; ++j) {
                s[i][j] = __expf(s[i][j] - m_new);
                rs += s[i][j];
            }
            rs += __shfl_xor(rs, 1, 64);
            rs += __shfl_xor(rs, 2, 64);
            rs += __shfl_xor(rs, 4, 64);
            rs += __shfl_xor(rs, 8, 64);
            l_i[i] = l_i[i] * alpha + rs;
            m_i[i] = m_new;
#pragma unroll
            for (int j = 0; j < 4; ++j) o[i][j] *= alpha;
        }

#pragma unroll
        for (int kc4 = 0; kc4 < 16; ++kc4) {
            int src = (lane & 48) + kc4;
#pragma unroll
            for (int jj = 0; jj < 4; ++jj) {
                float4 vv = *(const float4*)&Vs[kc4 * 4 + jj][tx * 4];
                float p0 = __shfl(s[0][jj], src, 64);
                float p1 = __shfl(s[1][jj], src, 64);
                float p2 = __shfl(s[2][jj], src, 64);
                float p3 = __shfl(s[3][jj], src, 64);
                o[0][0] += p0 * vv.x; o[0][1] += p0 * vv.y; o[0][2] += p0 * vv.z; o[0][3] += p0 * vv.w;
                o[1][0] += p1 * vv.x; o[1][1] += p1 * vv.y; o[1][2] += p1 * vv.z; o[1][3] += p1 * vv.w;
                o[2][0] += p2 * vv.x; o[2][1] += p2 * vv.y; o[2][2] += p2 * vv.z; o[2][3] += p2 * vv.w;
                o[3][0] += p3 * vv.x; o[3][1] += p3 * vv.y; o[3][2] += p3 * vv.z; o[3][3] += p3 * vv.w;
            }
        }
    }

#pragma unroll
    for (int i = 0; i < 4; ++i) {
        int t = q0 + ty * 4 + i;
        if (t >= TDIM) continue;
        float inv = 1.f / l_i[i];
        u16 r0 = f2bf(o[i][0] * inv);
        u16 r1 = f2bf(o[i][1] * inv);
        u16 r2 = f2bf(o[i][2] * inv);
        u16 r3 = f2bf(o[i][3] * inv);
        u16* p = out + ((size_t)b * TDIM + t) * EDIM + h * DDIM + tx * 4;
        p[0] = r0; p[1] = r1; p[2] = r2; p[3] = r3;
    }
}

// ---------------------------------------------------------------------------
extern "C" void kernel_launch(void* const* d_in, const int* in_sizes, int n_in,
                              void* d_out, int out_size, void* d_ws, size_t ws_size,
                              hipStream_t stream)
{
    const float* x  = (const float*)d_in[0];
    const float* Wq = (const float*)d_in[1];
    const float* bq = (const float*)d_in[2];
    const float* Wk = (const float*)d_in[3];
    const float* bk = (const float*)d_in[4];
    const float* Wv = (const float*)d_in[5];
    const float* bv = (const float*)d_in[6];
    const float* Wo = (const float*)d_in[7];
    const float* bo = (const float*)d_in[8];
    float* out = (float*)d_out;

    const size_t qsz = (size_t)BDIM * HDIM * TDIM * DDIM;  // 18,907,136
    float* qf = (float*)d_ws;
    float* kf = qf + qsz;
    float* vf = kf + qsz;
    // bf16 x is dead after the QKV GEMM -> attention output reuses its region.
    u16* xb  = (u16*)(vf + qsz);                 // bf16 x,  [MPAD][E]
    u16* abb = xb;                               // bf16 attn-out, aliases xb
    u16* wtq = xb + (size_t)MPAD * EDIM;         // bf16 W^T, [N][K] each
    u16* wtk = wtq + (size_t)EDIM * EDIM;
    u16* wtv = wtk + (size_t)EDIM * EDIM;
    u16* wto = wtv + (size_t)EDIM * EDIM;
    // total ws: 226.9 MB (qkv fp32) + 38.0 MB (bf16 acts, shared) + 8.4 MB (bf16 W)
    //         = 273.3 MB  — below the 302.5 MB proven available in round 1.

    cast_x<<<(MDIM * EDIM / 8 + 255) / 256, 256, 0, stream>>>(x, xb, MDIM * EDIM);
    cast_wt<<<dim3(32, 32, 4), 256, 0, stream>>>(Wq, Wk, Wv, Wo, wtq, wtk, wtv, wto);

    gemm_bf16<<<dim3(EDIM / 128, MTILES, 3), 256, 0, stream>>>(
        xb, wtq, wtk, wtv, bq, bk, bv, qf, kf, vf, 0);

    attn_fp32<<<dim3((TDIM + 63) / 64, HDIM, BDIM), 256, 0, stream>>>(qf, kf, vf, abb);

    gemm_bf16<<<dim3(EDIM / 128, MTILES, 1), 256, 0, stream>>>(
        abb, wto, wto, wto, bo, bo, bo, out, out, out, 1);
}

// Round 4
// 631.814 us; speedup vs baseline: 6.6736x; 2.4994x over previous
//
#include <hip/hip_runtime.h>
#include <cmath>

#define BDIM 32
#define TDIM 577
#define TPAD 640
#define EDIM 1024
#define HDIM 16
#define DDIM 64
#define MDIM (BDIM * TDIM)     // 18464
#define MTILES 145
#define MPAD (MTILES * 128)    // 18560

typedef unsigned short u16;
typedef __bf16 bf16x8 __attribute__((ext_vector_type(8)));
typedef float f32x4 __attribute__((ext_vector_type(4)));
typedef u16 u16x8 __attribute__((ext_vector_type(8)));

// fp32 -> bf16 round-to-nearest-even (matches numpy/jax)
__device__ __forceinline__ u16 f2bf(float f) {
    unsigned int u = __float_as_uint(f);
    u = (u + 0x7FFFu + ((u >> 16) & 1u)) >> 16;
    return (u16)u;
}

// async global->LDS, 16B per lane. LDS dest is wave-uniform base; HW adds lane*16.
__device__ __forceinline__ void gload_lds16(const void* g, void* l) {
    __builtin_amdgcn_global_load_lds(
        (const __attribute__((address_space(1))) unsigned int*)g,
        (__attribute__((address_space(3))) unsigned int*)l, 16, 0, 0);
}

// ---------------------------------------------------------------------------
// cast x (fp32 [M,E]) -> bf16
// ---------------------------------------------------------------------------
__global__ __launch_bounds__(256) void cast_x(const float* __restrict__ x,
                                              u16* __restrict__ o, int nelem)
{
    int i = (blockIdx.x * 256 + threadIdx.x) * 8;
    if (i >= nelem) return;
    float4 a = *(const float4*)(x + i);
    float4 b = *(const float4*)(x + i + 4);
    u16x8 r;
    r[0] = f2bf(a.x); r[1] = f2bf(a.y); r[2] = f2bf(a.z); r[3] = f2bf(a.w);
    r[4] = f2bf(b.x); r[5] = f2bf(b.y); r[6] = f2bf(b.z); r[7] = f2bf(b.w);
    *(u16x8*)(o + i) = r;
}

// ---------------------------------------------------------------------------
// cast + transpose weights: W fp32 [K,N] -> Wt bf16 [N,K]
// ---------------------------------------------------------------------------
__global__ __launch_bounds__(256) void cast_wt(
    const float* __restrict__ W0, const float* __restrict__ W1,
    const float* __restrict__ W2, const float* __restrict__ W3,
    u16* __restrict__ T0, u16* __restrict__ T1,
    u16* __restrict__ T2, u16* __restrict__ T3)
{
    __shared__ float tile[32][33];
    const int z = blockIdx.z;
    const float* __restrict__ W = (z == 0) ? W0 : (z == 1) ? W1 : (z == 2) ? W2 : W3;
    u16* __restrict__ T = (z == 0) ? T0 : (z == 1) ? T1 : (z == 2) ? T2 : T3;
    const int bn = blockIdx.x * 32;
    const int bk = blockIdx.y * 32;
    const int tx = threadIdx.x & 31, ty = threadIdx.x >> 5;
#pragma unroll
    for (int p = 0; p < 4; ++p) {
        int k = bk + p * 8 + ty;
        tile[p * 8 + ty][tx] = W[(size_t)k * EDIM + bn + tx];
    }
    __syncthreads();
#pragma unroll
    for (int p = 0; p < 4; ++p) {
        int n = bn + p * 8 + ty;
        T[(size_t)n * EDIM + bk + tx] = f2bf(tile[tx][p * 8 + ty]);
    }
}

// ---------------------------------------------------------------------------
// bf16 MFMA GEMM (m97 structure): C[M,N] = A[M,K] @ Wt[N,K]^T + bias
// mode 0 (QKV): bf16 out; z0/z1 -> [B,H,TPAD,D]; z2 -> V^T [B,H,D,TPAD]
// mode 1 (out-proj): fp32 row-major [M,N]
// ---------------------------------------------------------------------------
__global__ __launch_bounds__(256) void gemm_bf16(
    const u16* __restrict__ A,
    const u16* __restrict__ W0, const u16* __restrict__ W1, const u16* __restrict__ W2,
    const float* __restrict__ b0, const float* __restrict__ b1, const float* __restrict__ b2,
    void* __restrict__ o0, void* __restrict__ o1, void* __restrict__ o2,
    int mode)
{
    __shared__ u16 As[128 * 32];
    __shared__ u16 Bs[128 * 32];

    const int z = blockIdx.z;
    const u16* __restrict__ Wt     = (z == 0) ? W0 : ((z == 1) ? W1 : W2);
    const float* __restrict__ bias = (z == 0) ? b0 : ((z == 1) ? b1 : b2);
    void* __restrict__ dst         = (z == 0) ? o0 : ((z == 1) ? o1 : o2);

    const int tid = threadIdx.x;
    const int wave = tid >> 6;
    const int lane = tid & 63;
    const int mlane = lane & 15;
    const int quad = lane >> 4;
    const int wm = wave >> 1;
    const int wn = wave & 1;
    const int m0 = blockIdx.y * 128;
    const int n0 = blockIdx.x * 128;

    f32x4 acc[4][4];
#pragma unroll
    for (int i = 0; i < 4; ++i)
#pragma unroll
        for (int j = 0; j < 4; ++j) acc[i][j] = (f32x4)(0.f);

    for (int k0 = 0; k0 < EDIM; k0 += 32) {
#pragma unroll
        for (int r = 0; r < 2; ++r) {
            int c = r * 256 + tid;
            int row = c >> 2, col = (c & 3) * 8;
            gload_lds16(A + (size_t)(m0 + row) * EDIM + k0 + col,
                        &As[(r * 256 + wave * 64) * 8]);
            gload_lds16(Wt + (size_t)(n0 + row) * EDIM + k0 + col,
                        &Bs[(r * 256 + wave * 64) * 8]);
        }
        __syncthreads();

        bf16x8 af[4], bf[4];
#pragma unroll
        for (int t = 0; t < 4; ++t) {
            af[t] = *(const bf16x8*)&As[(wm * 64 + t * 16 + mlane) * 32 + quad * 8];
            bf[t] = *(const bf16x8*)&Bs[(wn * 64 + t * 16 + mlane) * 32 + quad * 8];
        }
#pragma unroll
        for (int i = 0; i < 4; ++i)
#pragma unroll
            for (int j = 0; j < 4; ++j)
                acc[i][j] = __builtin_amdgcn_mfma_f32_16x16x32_bf16(af[i], bf[j], acc[i][j], 0, 0, 0);
        __syncthreads();
    }

    // epilogue: C/D layout col = lane&15, row = quad*4 + reg
#pragma unroll
    for (int j = 0; j < 4; ++j) {
        int n = n0 + wn * 64 + j * 16 + mlane;
        float bv = bias[n];
        if (mode == 1) {
            float* df = (float*)dst;
#pragma unroll
            for (int i = 0; i < 4; ++i) {
                int mb = m0 + wm * 64 + i * 16 + quad * 4;
#pragma unroll
                for (int r = 0; r < 4; ++r) {
                    int gm = mb + r;
                    if (gm < MDIM) df[(size_t)gm * EDIM + n] = acc[i][j][r] + bv;
                }
            }
        } else {
            u16* db = (u16*)dst;
            int h = n >> 6, d = n & 63;
#pragma unroll
            for (int i = 0; i < 4; ++i) {
                int mb = m0 + wm * 64 + i * 16 + quad * 4;
#pragma unroll
                for (int r = 0; r < 4; ++r) {
                    int gm = mb + r;
                    if (gm < MDIM) {
                        int b = gm / TDIM, t = gm - b * TDIM;
                        u16 val = f2bf(acc[i][j][r] + bv);
                        if (z == 2)
                            db[((size_t)(b * HDIM + h) * DDIM + d) * TPAD + t] = val;
                        else
                            db[((size_t)(b * HDIM + h) * TPAD + t) * DDIM + d] = val;
                    }
                }
            }
        }
    }
}

// ---------------------------------------------------------------------------
// bf16 MFMA flash attention. Block = (b,h), 64 q rows, 4 waves x 16 rows.
// K/V^T staged per 64-chunk via global_load_lds into split panels [kc][row][32]
// (m97 LDS addressing). S=QK^T MFMA -> register online softmax (16-lane xor
// shuffles) -> P via LDS round-trip (C-layout -> A-layout, rows padded to 36)
// -> PV MFMA. OOB t rows contain poison/stale bf16 (finite); S cols >= T are
// masked to -inf, OOB q rows computed then discarded (row-isolated in MFMA).
// ---------------------------------------------------------------------------
__global__ __launch_bounds__(256) void attn_mfma(
    const u16* __restrict__ qg, const u16* __restrict__ kg,
    const u16* __restrict__ vtg, u16* __restrict__ outg)
{
    __shared__ u16 Qs[4096];    // [kc][t64][32]
    __shared__ u16 Ks[4096];    // [kc][n64][32]
    __shared__ u16 Vts[4096];   // [kc][d64][32]  (kc = kv-index panel)
    __shared__ u16 Ps[4608];    // 4 waves * 2 panels * 16 rows * 36 (padded)

    const int tid = threadIdx.x;
    const int wave = tid >> 6;
    const int lane = tid & 63;
    const int ml = lane & 15;
    const int quad = lane >> 4;
    const int h = blockIdx.y, b = blockIdx.z;
    const int q0 = blockIdx.x * 64;
    const u16* qb = qg + ((size_t)b * HDIM + h) * TPAD * DDIM;
    const u16* kb = kg + ((size_t)b * HDIM + h) * TPAD * DDIM;
    const u16* vb = vtg + ((size_t)b * HDIM + h) * DDIM * TPAD;

    // stage Q once: chunk c -> (row=(c>>2)&63, kc=c>>8, d8=c&3)
#pragma unroll
    for (int r = 0; r < 2; ++r) {
        int c = r * 256 + tid;
        int row = (c >> 2) & 63, kc = c >> 8, d8 = c & 3;
        gload_lds16(qb + (size_t)(q0 + row) * DDIM + kc * 32 + d8 * 8,
                    &Qs[(r * 256 + wave * 64) * 8]);
    }
    __syncthreads();

    bf16x8 aq0 = *(const bf16x8*)&Qs[(wave * 16 + ml) * 32 + quad * 8];
    bf16x8 aq1 = *(const bf16x8*)&Qs[2048 + (wave * 16 + ml) * 32 + quad * 8];

    f32x4 oacc[4];
#pragma unroll
    for (int dt = 0; dt < 4; ++dt) oacc[dt] = (f32x4)(0.f);
    float m_i[4], l_i[4];
#pragma unroll
    for (int r = 0; r < 4; ++r) { m_i[r] = -INFINITY; l_i[r] = 0.f; }

    for (int kv0 = 0; kv0 < TDIM; kv0 += 64) {
        __syncthreads();   // protect prior-iteration Ks/Vts reads
#pragma unroll
        for (int r = 0; r < 2; ++r) {
            int c = r * 256 + tid;
            int row = (c >> 2) & 63, kc = c >> 8, d8 = c & 3;
            gload_lds16(kb + (size_t)(kv0 + row) * DDIM + kc * 32 + d8 * 8,
                        &Ks[(r * 256 + wave * 64) * 8]);
            gload_lds16(vb + (size_t)row * TPAD + kv0 + kc * 32 + d8 * 8,
                        &Vts[(r * 256 + wave * 64) * 8]);
        }
        __syncthreads();

        // S = Q K^T : 4 n-tiles x 2 k-steps
        f32x4 sacc[4];
#pragma unroll
        for (int jt = 0; jt < 4; ++jt) {
            bf16x8 bk0 = *(const bf16x8*)&Ks[(jt * 16 + ml) * 32 + quad * 8];
            bf16x8 bk1 = *(const bf16x8*)&Ks[2048 + (jt * 16 + ml) * 32 + quad * 8];
            f32x4 sa = (f32x4)(0.f);
            sa = __builtin_amdgcn_mfma_f32_16x16x32_bf16(aq0, bk0, sa, 0, 0, 0);
            sa = __builtin_amdgcn_mfma_f32_16x16x32_bf16(aq1, bk1, sa, 0, 0, 0);
            sacc[jt] = sa;
        }

        // online softmax per row (rows quad*4+r, cols across 16 lanes x 4 tiles)
        float p[4][4];   // [jt][r]
#pragma unroll
        for (int r = 0; r < 4; ++r) {
            float cm = -INFINITY;
#pragma unroll
            for (int jt = 0; jt < 4; ++jt) {
                bool valid = (kv0 + jt * 16 + ml) < TDIM;
                float sv = valid ? sacc[jt][r] * 0.125f : -INFINITY;
                p[jt][r] = sv;
                cm = fmaxf(cm, sv);
            }
            cm = fmaxf(cm, __shfl_xor(cm, 1, 64));
            cm = fmaxf(cm, __shfl_xor(cm, 2, 64));
            cm = fmaxf(cm, __shfl_xor(cm, 4, 64));
            cm = fmaxf(cm, __shfl_xor(cm, 8, 64));
            float mn = fmaxf(m_i[r], cm);
            float alpha = __expf(m_i[r] - mn);
            float rs = 0.f;
#pragma unroll
            for (int jt = 0; jt < 4; ++jt) {
                float e = __expf(p[jt][r] - mn);
                p[jt][r] = e;
                rs += e;
            }
            rs += __shfl_xor(rs, 1, 64);
            rs += __shfl_xor(rs, 2, 64);
            rs += __shfl_xor(rs, 4, 64);
            rs += __shfl_xor(rs, 8, 64);
            l_i[r] = l_i[r] * alpha + rs;
            m_i[r] = mn;
#pragma unroll
            for (int dt = 0; dt < 4; ++dt) oacc[dt][r] *= alpha;
        }

        // P: C-layout regs -> LDS [kc][m16][36] per wave -> A-layout frags
#pragma unroll
        for (int jt = 0; jt < 4; ++jt)
#pragma unroll
            for (int r = 0; r < 4; ++r)
                Ps[wave * 1152 + (jt >> 1) * 576 + (quad * 4 + r) * 36 + (jt & 1) * 16 + ml]
                    = f2bf(p[jt][r]);
        __syncthreads();

        bf16x8 pf0 = *(const bf16x8*)&Ps[wave * 1152 + ml * 36 + quad * 8];
        bf16x8 pf1 = *(const bf16x8*)&Ps[wave * 1152 + 576 + ml * 36 + quad * 8];

        // O += P V : 4 d-tiles x 2 k-steps (contraction over kv)
#pragma unroll
        for (int dt = 0; dt < 4; ++dt) {
            bf16x8 bv0 = *(const bf16x8*)&Vts[(dt * 16 + ml) * 32 + quad * 8];
            bf16x8 bv1 = *(const bf16x8*)&Vts[2048 + (dt * 16 + ml) * 32 + quad * 8];
            oacc[dt] = __builtin_amdgcn_mfma_f32_16x16x32_bf16(pf0, bv0, oacc[dt], 0, 0, 0);
            oacc[dt] = __builtin_amdgcn_mfma_f32_16x16x32_bf16(pf1, bv1, oacc[dt], 0, 0, 0);
        }
    }

    // epilogue: normalize, write bf16 row-major [M][E]
#pragma unroll
    for (int r = 0; r < 4; ++r) {
        int t = q0 + wave * 16 + quad * 4 + r;
        if (t >= TDIM) continue;
        float inv = 1.f / l_i[r];
        size_t rowoff = ((size_t)b * TDIM + t) * EDIM + h * DDIM;
#pragma unroll
        for (int dt = 0; dt < 4; ++dt)
            outg[rowoff + dt * 16 + ml] = f2bf(oacc[dt][r] * inv);
    }
}

// ---------------------------------------------------------------------------
extern "C" void kernel_launch(void* const* d_in, const int* in_sizes, int n_in,
                              void* d_out, int out_size, void* d_ws, size_t ws_size,
                              hipStream_t stream)
{
    const float* x  = (const float*)d_in[0];
    const float* Wq = (const float*)d_in[1];
    const float* bq = (const float*)d_in[2];
    const float* Wk = (const float*)d_in[3];
    const float* bk = (const float*)d_in[4];
    const float* Wv = (const float*)d_in[5];
    const float* bv = (const float*)d_in[6];
    const float* Wo = (const float*)d_in[7];
    const float* bo = (const float*)d_in[8];
    float* out = (float*)d_out;

    const size_t hsz = (size_t)BDIM * HDIM * TPAD * DDIM;  // 20,971,520 elems
    u16* qb  = (u16*)d_ws;                     // bf16 [B,H,TPAD,D]
    u16* kb  = qb + hsz;                       // bf16 [B,H,TPAD,D]
    u16* vtb = kb + hsz;                       // bf16 [B,H,D,TPAD]
    u16* xb  = vtb + hsz;                      // bf16 x [MPAD][E]
    u16* abb = xb;                             // attn out aliases xb (xb dead by then)
    u16* wtq = xb + (size_t)MPAD * EDIM;       // bf16 W^T [N][K]
    u16* wtk = wtq + (size_t)EDIM * EDIM;
    u16* wtv = wtk + (size_t)EDIM * EDIM;
    u16* wto = wtv + (size_t)EDIM * EDIM;
    // ws: 125.8 MB (qkv bf16) + 38.0 MB (acts) + 8.4 MB (weights) = 172.2 MB

    cast_x<<<(MDIM * EDIM / 8 + 255) / 256, 256, 0, stream>>>(x, xb, MDIM * EDIM);
    cast_wt<<<dim3(32, 32, 4), 256, 0, stream>>>(Wq, Wk, Wv, Wo, wtq, wtk, wtv, wto);

    gemm_bf16<<<dim3(EDIM / 128, MTILES, 3), 256, 0, stream>>>(
        xb, wtq, wtk, wtv, bq, bk, bv, (void*)qb, (void*)kb, (void*)vtb, 0);

    attn_mfma<<<dim3(TPAD / 64, HDIM, BDIM), 256, 0, stream>>>(qb, kb, vtb, abb);

    gemm_bf16<<<dim3(EDIM / 128, MTILES, 1), 256, 0, stream>>>(
        abb, wto, wto, wto, bo, bo, bo, (void*)out, (void*)out, (void*)out, 1);
}

// Round 5
// 612.160 us; speedup vs baseline: 6.8879x; 1.0321x over previous
//
#include <hip/hip_runtime.h>
#include <cmath>

#define BDIM 32
#define TDIM 577
#define TPAD 640
#define EDIM 1024
#define HDIM 16
#define DDIM 64
#define MDIM (BDIM * TDIM)     // 18464
#define MTILES 145
#define MPAD (MTILES * 128)    // 18560

typedef unsigned short u16;
typedef __bf16 bf16x8 __attribute__((ext_vector_type(8)));
typedef float f32x4 __attribute__((ext_vector_type(4)));
typedef u16 u16x8 __attribute__((ext_vector_type(8)));

// fp32 -> bf16 round-to-nearest-even (matches numpy/jax)
__device__ __forceinline__ u16 f2bf(float f) {
    unsigned int u = __float_as_uint(f);
    u = (u + 0x7FFFu + ((u >> 16) & 1u)) >> 16;
    return (u16)u;
}

// async global->LDS, 16B per lane. LDS dest is wave-uniform base; HW adds lane*16.
__device__ __forceinline__ void gload_lds16(const void* g, void* l) {
    __builtin_amdgcn_global_load_lds(
        (const __attribute__((address_space(1))) unsigned int*)g,
        (__attribute__((address_space(3))) unsigned int*)l, 16, 0, 0);
}

// ---------------------------------------------------------------------------
// cast x (fp32 [M,E]) -> bf16
// ---------------------------------------------------------------------------
__global__ __launch_bounds__(256) void cast_x(const float* __restrict__ x,
                                              u16* __restrict__ o, int nelem)
{
    int i = (blockIdx.x * 256 + threadIdx.x) * 8;
    if (i >= nelem) return;
    float4 a = *(const float4*)(x + i);
    float4 b = *(const float4*)(x + i + 4);
    u16x8 r;
    r[0] = f2bf(a.x); r[1] = f2bf(a.y); r[2] = f2bf(a.z); r[3] = f2bf(a.w);
    r[4] = f2bf(b.x); r[5] = f2bf(b.y); r[6] = f2bf(b.z); r[7] = f2bf(b.w);
    *(u16x8*)(o + i) = r;
}

// ---------------------------------------------------------------------------
// cast + transpose weights: W fp32 [K,N] -> Wt bf16 [N,K]
// ---------------------------------------------------------------------------
__global__ __launch_bounds__(256) void cast_wt(
    const float* __restrict__ W0, const float* __restrict__ W1,
    const float* __restrict__ W2, const float* __restrict__ W3,
    u16* __restrict__ T0, u16* __restrict__ T1,
    u16* __restrict__ T2, u16* __restrict__ T3)
{
    __shared__ float tile[32][33];
    const int z = blockIdx.z;
    const float* __restrict__ W = (z == 0) ? W0 : (z == 1) ? W1 : (z == 2) ? W2 : W3;
    u16* __restrict__ T = (z == 0) ? T0 : (z == 1) ? T1 : (z == 2) ? T2 : T3;
    const int bn = blockIdx.x * 32;
    const int bk = blockIdx.y * 32;
    const int tx = threadIdx.x & 31, ty = threadIdx.x >> 5;
#pragma unroll
    for (int p = 0; p < 4; ++p) {
        int k = bk + p * 8 + ty;
        tile[p * 8 + ty][tx] = W[(size_t)k * EDIM + bn + tx];
    }
    __syncthreads();
#pragma unroll
    for (int p = 0; p < 4; ++p) {
        int n = bn + p * 8 + ty;
        T[(size_t)n * EDIM + bk + tx] = f2bf(tile[tx][p * 8 + ty]);
    }
}

// ---------------------------------------------------------------------------
// bf16 MFMA GEMM: C[M,N] = A[M,K] @ Wt[N,K]^T + bias
// 128x128 tile, BK=64 (two 32-k panels [p][128][32] in LDS -> fragment
// ds_read_b128 keeps the uniform-8/bank pattern), 16 K-iters, 32 MFMA per
// wave per barrier interval (2x m97's work per vmcnt(0) drain).
// Panel-sequenced inner loop caps live fragments at 8 (VGPR <= 128 under
// __launch_bounds__(256,4)).
// mode 0 (QKV): bf16 out; z0/z1 -> [B,H,TPAD,D]; z2 -> V^T [B,H,D,TPAD]
// mode 1 (out-proj): fp32 row-major [M,N]
// ---------------------------------------------------------------------------
__global__ __launch_bounds__(256, 4) void gemm_bf16(
    const u16* __restrict__ A,
    const u16* __restrict__ W0, const u16* __restrict__ W1, const u16* __restrict__ W2,
    const float* __restrict__ b0, const float* __restrict__ b1, const float* __restrict__ b2,
    void* __restrict__ o0, void* __restrict__ o1, void* __restrict__ o2,
    int mode)
{
    __shared__ u16 As[128 * 64];   // 2 panels x [128][32], 16 KB
    __shared__ u16 Bs[128 * 64];

    const int z = blockIdx.z;
    const u16* __restrict__ Wt     = (z == 0) ? W0 : ((z == 1) ? W1 : W2);
    const float* __restrict__ bias = (z == 0) ? b0 : ((z == 1) ? b1 : b2);
    void* __restrict__ dst         = (z == 0) ? o0 : ((z == 1) ? o1 : o2);

    const int tid = threadIdx.x;
    const int wave = tid >> 6;
    const int lane = tid & 63;
    const int mlane = lane & 15;
    const int quad = lane >> 4;
    const int wm = wave >> 1;
    const int wn = wave & 1;
    const int m0 = blockIdx.y * 128;
    const int n0 = blockIdx.x * 128;

    f32x4 acc[4][4];
#pragma unroll
    for (int i = 0; i < 4; ++i)
#pragma unroll
        for (int j = 0; j < 4; ++j) acc[i][j] = (f32x4)(0.f);

    for (int k0 = 0; k0 < EDIM; k0 += 64) {
        // chunk c in [0,1024): panel p=c>>9, row=(c>>2)&127, j4=c&3
        // LDS offset = c*16B; global = row*EDIM + k0 + p*32 + j4*8
#pragma unroll
        for (int r = 0; r < 4; ++r) {
            int c = r * 256 + tid;
            int p = c >> 9, row = (c >> 2) & 127, j4 = c & 3;
            int koff = k0 + p * 32 + j4 * 8;
            gload_lds16(A + (size_t)(m0 + row) * EDIM + koff,
                        &As[(r * 256 + wave * 64) * 8]);
            gload_lds16(Wt + (size_t)(n0 + row) * EDIM + koff,
                        &Bs[(r * 256 + wave * 64) * 8]);
        }
        __syncthreads();   // drains vmcnt per barrier semantics

#pragma unroll
        for (int ks = 0; ks < 2; ++ks) {
            bf16x8 af[4], bfr[4];
#pragma unroll
            for (int t = 0; t < 4; ++t) {
                af[t]  = *(const bf16x8*)&As[ks * 4096 + (wm * 64 + t * 16 + mlane) * 32 + quad * 8];
                bfr[t] = *(const bf16x8*)&Bs[ks * 4096 + (wn * 64 + t * 16 + mlane) * 32 + quad * 8];
            }
#pragma unroll
            for (int i = 0; i < 4; ++i)
#pragma unroll
                for (int j = 0; j < 4; ++j)
                    acc[i][j] = __builtin_amdgcn_mfma_f32_16x16x32_bf16(af[i], bfr[j], acc[i][j], 0, 0, 0);
        }
        __syncthreads();
    }

    // epilogue: C/D layout col = lane&15, row = quad*4 + reg
#pragma unroll
    for (int j = 0; j < 4; ++j) {
        int n = n0 + wn * 64 + j * 16 + mlane;
        float bv = bias[n];
        if (mode == 1) {
            float* df = (float*)dst;
#pragma unroll
            for (int i = 0; i < 4; ++i) {
                int mb = m0 + wm * 64 + i * 16 + quad * 4;
#pragma unroll
                for (int r = 0; r < 4; ++r) {
                    int gm = mb + r;
                    if (gm < MDIM) df[(size_t)gm * EDIM + n] = acc[i][j][r] + bv;
                }
            }
        } else {
            u16* db = (u16*)dst;
            int h = n >> 6, d = n & 63;
#pragma unroll
            for (int i = 0; i < 4; ++i) {
                int mb = m0 + wm * 64 + i * 16 + quad * 4;
#pragma unroll
                for (int r = 0; r < 4; ++r) {
                    int gm = mb + r;
                    if (gm < MDIM) {
                        int b = gm / TDIM, t = gm - b * TDIM;
                        u16 val = f2bf(acc[i][j][r] + bv);
                        if (z == 2)
                            db[((size_t)(b * HDIM + h) * DDIM + d) * TPAD + t] = val;
                        else
                            db[((size_t)(b * HDIM + h) * TPAD + t) * DDIM + d] = val;
                    }
                }
            }
        }
    }
}

// ---------------------------------------------------------------------------
// bf16 MFMA flash attention (unchanged from round 4).
// ---------------------------------------------------------------------------
__global__ __launch_bounds__(256) void attn_mfma(
    const u16* __restrict__ qg, const u16* __restrict__ kg,
    const u16* __restrict__ vtg, u16* __restrict__ outg)
{
    __shared__ u16 Qs[4096];    // [kc][t64][32]
    __shared__ u16 Ks[4096];    // [kc][n64][32]
    __shared__ u16 Vts[4096];   // [kc][d64][32]
    __shared__ u16 Ps[4608];    // 4 waves * 2 panels * 16 rows * 36 (padded)

    const int tid = threadIdx.x;
    const int wave = tid >> 6;
    const int lane = tid & 63;
    const int ml = lane & 15;
    const int quad = lane >> 4;
    const int h = blockIdx.y, b = blockIdx.z;
    const int q0 = blockIdx.x * 64;
    const u16* qb = qg + ((size_t)b * HDIM + h) * TPAD * DDIM;
    const u16* kb = kg + ((size_t)b * HDIM + h) * TPAD * DDIM;
    const u16* vb = vtg + ((size_t)b * HDIM + h) * DDIM * TPAD;

#pragma unroll
    for (int r = 0; r < 2; ++r) {
        int c = r * 256 + tid;
        int row = (c >> 2) & 63, kc = c >> 8, d8 = c & 3;
        gload_lds16(qb + (size_t)(q0 + row) * DDIM + kc * 32 + d8 * 8,
                    &Qs[(r * 256 + wave * 64) * 8]);
    }
    __syncthreads();

    bf16x8 aq0 = *(const bf16x8*)&Qs[(wave * 16 + ml) * 32 + quad * 8];
    bf16x8 aq1 = *(const bf16x8*)&Qs[2048 + (wave * 16 + ml) * 32 + quad * 8];

    f32x4 oacc[4];
#pragma unroll
    for (int dt = 0; dt < 4; ++dt) oacc[dt] = (f32x4)(0.f);
    float m_i[4], l_i[4];
#pragma unroll
    for (int r = 0; r < 4; ++r) { m_i[r] = -INFINITY; l_i[r] = 0.f; }

    for (int kv0 = 0; kv0 < TDIM; kv0 += 64) {
        __syncthreads();
#pragma unroll
        for (int r = 0; r < 2; ++r) {
            int c = r * 256 + tid;
            int row = (c >> 2) & 63, kc = c >> 8, d8 = c & 3;
            gload_lds16(kb + (size_t)(kv0 + row) * DDIM + kc * 32 + d8 * 8,
                        &Ks[(r * 256 + wave * 64) * 8]);
            gload_lds16(vb + (size_t)row * TPAD + kv0 + kc * 32 + d8 * 8,
                        &Vts[(r * 256 + wave * 64) * 8]);
        }
        __syncthreads();

        f32x4 sacc[4];
#pragma unroll
        for (int jt = 0; jt < 4; ++jt) {
            bf16x8 bk0 = *(const bf16x8*)&Ks[(jt * 16 + ml) * 32 + quad * 8];
            bf16x8 bk1 = *(const bf16x8*)&Ks[2048 + (jt * 16 + ml) * 32 + quad * 8];
            f32x4 sa = (f32x4)(0.f);
            sa = __builtin_amdgcn_mfma_f32_16x16x32_bf16(aq0, bk0, sa, 0, 0, 0);
            sa = __builtin_amdgcn_mfma_f32_16x16x32_bf16(aq1, bk1, sa, 0, 0, 0);
            sacc[jt] = sa;
        }

        float p[4][4];
#pragma unroll
        for (int r = 0; r < 4; ++r) {
            float cm = -INFINITY;
#pragma unroll
            for (int jt = 0; jt < 4; ++jt) {
                bool valid = (kv0 + jt * 16 + ml) < TDIM;
                float sv = valid ? sacc[jt][r] * 0.125f : -INFINITY;
                p[jt][r] = sv;
                cm = fmaxf(cm, sv);
            }
            cm = fmaxf(cm, __shfl_xor(cm, 1, 64));
            cm = fmaxf(cm, __shfl_xor(cm, 2, 64));
            cm = fmaxf(cm, __shfl_xor(cm, 4, 64));
            cm = fmaxf(cm, __shfl_xor(cm, 8, 64));
            float mn = fmaxf(m_i[r], cm);
            float alpha = __expf(m_i[r] - mn);
            float rs = 0.f;
#pragma unroll
            for (int jt = 0; jt < 4; ++jt) {
                float e = __expf(p[jt][r] - mn);
                p[jt][r] = e;
                rs += e;
            }
            rs += __shfl_xor(rs, 1, 64);
            rs += __shfl_xor(rs, 2, 64);
            rs += __shfl_xor(rs, 4, 64);
            rs += __shfl_xor(rs, 8, 64);
            l_i[r] = l_i[r] * alpha + rs;
            m_i[r] = mn;
#pragma unroll
            for (int dt = 0; dt < 4; ++dt) oacc[dt][r] *= alpha;
        }

#pragma unroll
        for (int jt = 0; jt < 4; ++jt)
#pragma unroll
            for (int r = 0; r < 4; ++r)
                Ps[wave * 1152 + (jt >> 1) * 576 + (quad * 4 + r) * 36 + (jt & 1) * 16 + ml]
                    = f2bf(p[jt][r]);
        __syncthreads();

        bf16x8 pf0 = *(const bf16x8*)&Ps[wave * 1152 + ml * 36 + quad * 8];
        bf16x8 pf1 = *(const bf16x8*)&Ps[wave * 1152 + 576 + ml * 36 + quad * 8];

#pragma unroll
        for (int dt = 0; dt < 4; ++dt) {
            bf16x8 bv0 = *(const bf16x8*)&Vts[(dt * 16 + ml) * 32 + quad * 8];
            bf16x8 bv1 = *(const bf16x8*)&Vts[2048 + (dt * 16 + ml) * 32 + quad * 8];
            oacc[dt] = __builtin_amdgcn_mfma_f32_16x16x32_bf16(pf0, bv0, oacc[dt], 0, 0, 0);
            oacc[dt] = __builtin_amdgcn_mfma_f32_16x16x32_bf16(pf1, bv1, oacc[dt], 0, 0, 0);
        }
    }

#pragma unroll
    for (int r = 0; r < 4; ++r) {
        int t = q0 + wave * 16 + quad * 4 + r;
        if (t >= TDIM) continue;
        float inv = 1.f / l_i[r];
        size_t rowoff = ((size_t)b * TDIM + t) * EDIM + h * DDIM;
#pragma unroll
        for (int dt = 0; dt < 4; ++dt)
            outg[rowoff + dt * 16 + ml] = f2bf(oacc[dt][r] * inv);
    }
}

// ---------------------------------------------------------------------------
extern "C" void kernel_launch(void* const* d_in, const int* in_sizes, int n_in,
                              void* d_out, int out_size, void* d_ws, size_t ws_size,
                              hipStream_t stream)
{
    const float* x  = (const float*)d_in[0];
    const float* Wq = (const float*)d_in[1];
    const float* bq = (const float*)d_in[2];
    const float* Wk = (const float*)d_in[3];
    const float* bk = (const float*)d_in[4];
    const float* Wv = (const float*)d_in[5];
    const float* bv = (const float*)d_in[6];
    const float* Wo = (const float*)d_in[7];
    const float* bo = (const float*)d_in[8];
    float* out = (float*)d_out;

    const size_t hsz = (size_t)BDIM * HDIM * TPAD * DDIM;  // 20,971,520 elems
    u16* qb  = (u16*)d_ws;                     // bf16 [B,H,TPAD,D]
    u16* kb  = qb + hsz;                       // bf16 [B,H,TPAD,D]
    u16* vtb = kb + hsz;                       // bf16 [B,H,D,TPAD]
    u16* xb  = vtb + hsz;                      // bf16 x [MPAD][E]
    u16* abb = xb;                             // attn out aliases xb (xb dead by then)
    u16* wtq = xb + (size_t)MPAD * EDIM;       // bf16 W^T [N][K]
    u16* wtk = wtq + (size_t)EDIM * EDIM;
    u16* wtv = wtk + (size_t)EDIM * EDIM;
    u16* wto = wtv + (size_t)EDIM * EDIM;
    // ws: 125.8 MB + 38.0 MB + 8.4 MB = 172.2 MB

    cast_x<<<(MDIM * EDIM / 8 + 255) / 256, 256, 0, stream>>>(x, xb, MDIM * EDIM);
    cast_wt<<<dim3(32, 32, 4), 256, 0, stream>>>(Wq, Wk, Wv, Wo, wtq, wtk, wtv, wto);

    gemm_bf16<<<dim3(EDIM / 128, MTILES, 3), 256, 0, stream>>>(
        xb, wtq, wtk, wtv, bq, bk, bv, (void*)qb, (void*)kb, (void*)vtb, 0);

    attn_mfma<<<dim3(TPAD / 64, HDIM, BDIM), 256, 0, stream>>>(qb, kb, vtb, abb);

    gemm_bf16<<<dim3(EDIM / 128, MTILES, 1), 256, 0, stream>>>(
        abb, wto, wto, wto, bo, bo, bo, (void*)out, (void*)out, (void*)out, 1);
}